// Round 10
// baseline (117.131 us; speedup 1.0000x reference)
//
#include <hip/hip_runtime.h>

// ROIAlign (FPN, multi-level) for MI355X.
// Inputs (f32): fm2 [4,256,256,256] s4 | fm3 [4,128,128,256] s8
//               fm4 [4,64,64,256] s16  | fm5 [4,32,32,256] s32
//               rois [4,512,4] (x1,y1,x2,y2)
// Output (f32): [4,512,256,7,7]
//
// R9 -> R10: clean occupancy A/B. Identical structure to R9 (= R6, the
// 64 us best). Only change: __launch_bounds__(512,6) forces VGPR <= 85 so
// 3 blocks/CU fit (24 waves, 1.5x) -- LDS (52 KB) already allowed 3, VGPR
// (~100) was the binding limit at 2. R7's occupancy push regressed but was
// confounded (2x instruction stream); this isolates occupancy alone.
// Pre-commit: null/regress => latency equilibrium, R6 is the roofline.

constexpr int S     = 7;
constexpr int SS    = 49;
constexpr int CCH   = 256;
constexpr int NROI  = 512;
constexpr int BATCH = 4;

__global__ __launch_bounds__(512, 6) void roialign_kernel(
    const float* __restrict__ fm2, const float* __restrict__ fm3,
    const float* __restrict__ fm4, const float* __restrict__ fm5,
    const float* __restrict__ rois, float* __restrict__ out)
{
    __shared__ float    tile[SS * CCH];   // 50176 B, XOR-swizzled channel index
    __shared__ float    s_wyh[14], s_wyl[14], s_wxh[14], s_wxl[14];
    __shared__ unsigned s_ry0[14], s_ry1[14], s_cx0[14], s_cx1[14];
    __shared__ float    s_bw[SS][4];      // merged row weights per bin (pre-scaled 0.25)
    __shared__ float    s_bu[SS][4];      // merged col weights per bin
    __shared__ unsigned s_bm[SS];         // survive mask: rows bits0-3, cols bits4-7

    const int roi = blockIdx.x;           // 0 .. B*N-1
    const int b   = roi >> 9;

    // ---- wave-uniform prologue ----
    const float x1  = rois[roi * 4 + 0];
    const float y1v = rois[roi * 4 + 1];
    const float x2  = rois[roi * 4 + 2];
    const float y2v = rois[roi * 4 + 3];

    const float area = (y2v - y1v) * (x2 - x1);
    const float lraw = logf(sqrtf(area) * (1.0f / 224.0f)) * 1.4426950408889634f + 4.0f;
    int lvl = (int)rintf(lraw);
    lvl = lvl < 2 ? 2 : (lvl > 5 ? 5 : lvl);

    const float* fm; int H; float scale;
    if (lvl == 2)      { fm = fm2; H = 256; scale = 0.25f;    }
    else if (lvl == 3) { fm = fm3; H = 128; scale = 0.125f;   }
    else if (lvl == 4) { fm = fm4; H = 64;  scale = 0.0625f;  }
    else               { fm = fm5; H = 32;  scale = 0.03125f; }
    const int W = H;
    fm += (size_t)b * H * W * CCH;

    const float bx1 = x1 * scale, by1 = y1v * scale;
    const float rw  = fmaxf(x2 * scale - bx1, 1.0f);
    const float rh  = fmaxf(y2v * scale - by1, 1.0f);
    const float stx = rw * (1.0f / 7.0f);
    const float sty = rh * (1.0f / 7.0f);

    const int t = threadIdx.x;

    // ---- sample LUT: 14 y entries (wave 0) + 14 x entries (wave 1) ----
    if (t < 14) {
        const int k = t;
        const float yy = by1 + ((float)k + 0.5f) * 0.5f * sty;
        const float Hf = (float)H;
        const bool  v  = (yy > -1.0f) && (yy < Hf);
        const float yc = fminf(fmaxf(yy, 0.0f), Hf - 1.0f);
        const int   y0 = (int)floorf(yc);
        const int   y1i = min(y0 + 1, H - 1);
        const float ly = yc - (float)y0;
        s_wyl[k] = v ? ly : 0.0f;
        s_wyh[k] = v ? 1.0f - ly : 0.0f;
        s_ry0[k] = (unsigned)(y0  * W * (CCH * 4));   // byte offset of fm row
        s_ry1[k] = (unsigned)(y1i * W * (CCH * 4));
    } else if (t >= 64 && t < 78) {
        const int k = t - 64;
        const float xx = bx1 + ((float)k + 0.5f) * 0.5f * stx;
        const float Wf = (float)W;
        const bool  v  = (xx > -1.0f) && (xx < Wf);
        const float xc = fminf(fmaxf(xx, 0.0f), Wf - 1.0f);
        const int   x0 = (int)floorf(xc);
        const int   x1i = min(x0 + 1, W - 1);
        const float lx = xc - (float)x0;
        s_wxl[k] = v ? lx : 0.0f;
        s_wxh[k] = v ? 1.0f - lx : 0.0f;
        s_cx0[k] = (unsigned)(x0  * (CCH * 4));       // byte offset of fm col
        s_cx1[k] = (unsigned)(x1i * (CCH * 4));
    }
    __syncthreads();

    // ---- per-bin merged weights + survive mask (one thread per bin) ----
    if (t < SS) {
        const int sy = t / 7, sx = t - sy * 7;
        const int ky = sy << 1, kx = sx << 1;

        float w0 = s_wyh[ky], w1 = s_wyl[ky], w2 = s_wyh[ky + 1], w3 = s_wyl[ky + 1];
        {
            const unsigned rA = s_ry0[ky], rB = s_ry1[ky];
            const unsigned rC = s_ry0[ky + 1], rD = s_ry1[ky + 1];
            const bool eBA = (rB == rA);
            if (eBA) { w0 += w1; w1 = 0.f; }
            const bool eCA = (rC == rA);
            const bool eCB = !eCA && (rC == rB);
            if (eCA) w0 += w2; else if (eCB) w1 += w2;
            if (eCA || eCB) w2 = 0.f;
            const bool eDA = (rD == rA);
            const bool eDB = !eDA && (rD == rB);
            const bool eDC = !eDA && !eDB && (rD == rC);
            if (eDA) w0 += w3; else if (eDB) w1 += w3; else if (eDC) w2 += w3;
            if (eDA || eDB || eDC) w3 = 0.f;
        }
        float u0 = s_wxh[kx], u1 = s_wxl[kx], u2 = s_wxh[kx + 1], u3 = s_wxl[kx + 1];
        {
            const unsigned cA = s_cx0[kx], cB = s_cx1[kx];
            const unsigned cC = s_cx0[kx + 1], cD = s_cx1[kx + 1];
            const bool eBA = (cB == cA);
            if (eBA) { u0 += u1; u1 = 0.f; }
            const bool eCA = (cC == cA);
            const bool eCB = !eCA && (cC == cB);
            if (eCA) u0 += u2; else if (eCB) u1 += u2;
            if (eCA || eCB) u2 = 0.f;
            const bool eDA = (cD == cA);
            const bool eDB = !eDA && (cD == cB);
            const bool eDC = !eDA && !eDB && (cD == cC);
            if (eDA) u0 += u3; else if (eDB) u1 += u3; else if (eDC) u2 += u3;
            if (eDA || eDB || eDC) u3 = 0.f;
        }
        // fold the 2x2 bin-average (0.25) into the row weights
        s_bw[t][0] = w0 * 0.25f; s_bw[t][1] = w1 * 0.25f;
        s_bw[t][2] = w2 * 0.25f; s_bw[t][3] = w3 * 0.25f;
        s_bu[t][0] = u0; s_bu[t][1] = u1; s_bu[t][2] = u2; s_bu[t][3] = u3;
        s_bm[t] = (w0 != 0.f ? 0x01u : 0u) | (w1 != 0.f ? 0x02u : 0u)
                | (w2 != 0.f ? 0x04u : 0u) | (w3 != 0.f ? 0x08u : 0u)
                | (u0 != 0.f ? 0x10u : 0u) | (u1 != 0.f ? 0x20u : 0u)
                | (u2 != 0.f ? 0x40u : 0u) | (u3 != 0.f ? 0x80u : 0u);
    }
    __syncthreads();

    // ---- compute: one bin per wave-pass, 4 channels (float4) per lane ----
    const int lane = t & 63;
    const int wv   = t >> 6;                       // 0..7
    const unsigned cb = (unsigned)(lane << 4);     // byte offset within pixel

    const char* __restrict__ fmb = (const char*)fm;
    const float4 z4 = make_float4(0.f, 0.f, 0.f, 0.f);

    for (int bin = wv; bin < SS; bin += 8) {
        const int sy = bin / 7;
        const int sx = bin - sy * 7;
        const int ky = sy << 1, kx = sx << 1;

        // scalar survive mask -> wave-uniform s_cbranch guards
        const unsigned m = (unsigned)__builtin_amdgcn_readfirstlane((int)s_bm[bin]);

        const float w0 = s_bw[bin][0], w1 = s_bw[bin][1];
        const float w2 = s_bw[bin][2], w3 = s_bw[bin][3];
        const float u0 = s_bu[bin][0], u1 = s_bu[bin][1];
        const float u2 = s_bu[bin][2], u3 = s_bu[bin][3];

        const unsigned rA = s_ry0[ky],     rB = s_ry1[ky];
        const unsigned rC = s_ry0[ky + 1], rD = s_ry1[ky + 1];
        const unsigned cA = s_cx0[kx],     cB = s_cx1[kx];
        const unsigned cC = s_cx0[kx + 1], cD = s_cx1[kx + 1];

#define LD4(OFF) (*(const float4*)(fmb + (OFF)))
        float4 f00 = z4, f01 = z4, f02 = z4, f03 = z4;
        float4 f10 = z4, f11 = z4, f12 = z4, f13 = z4;
        float4 f20 = z4, f21 = z4, f22 = z4, f23 = z4;
        float4 f30 = z4, f31 = z4, f32 = z4, f33 = z4;

        if ((m & 0x11u) == 0x11u) f00 = LD4(rA + cA + cb);
        if ((m & 0x21u) == 0x21u) f01 = LD4(rA + cB + cb);
        if ((m & 0x41u) == 0x41u) f02 = LD4(rA + cC + cb);
        if ((m & 0x81u) == 0x81u) f03 = LD4(rA + cD + cb);
        if ((m & 0x12u) == 0x12u) f10 = LD4(rB + cA + cb);
        if ((m & 0x22u) == 0x22u) f11 = LD4(rB + cB + cb);
        if ((m & 0x42u) == 0x42u) f12 = LD4(rB + cC + cb);
        if ((m & 0x82u) == 0x82u) f13 = LD4(rB + cD + cb);
        if ((m & 0x14u) == 0x14u) f20 = LD4(rC + cA + cb);
        if ((m & 0x24u) == 0x24u) f21 = LD4(rC + cB + cb);
        if ((m & 0x44u) == 0x44u) f22 = LD4(rC + cC + cb);
        if ((m & 0x84u) == 0x84u) f23 = LD4(rC + cD + cb);
        if ((m & 0x18u) == 0x18u) f30 = LD4(rD + cA + cb);
        if ((m & 0x28u) == 0x28u) f31 = LD4(rD + cB + cb);
        if ((m & 0x48u) == 0x48u) f32 = LD4(rD + cC + cb);
        if ((m & 0x88u) == 0x88u) f33 = LD4(rD + cD + cb);
#undef LD4

        float4 acc = z4;
#define ACC4(Wt, F) { const float pw_ = (Wt); \
        acc.x = fmaf(pw_, (F).x, acc.x); acc.y = fmaf(pw_, (F).y, acc.y); \
        acc.z = fmaf(pw_, (F).z, acc.z); acc.w = fmaf(pw_, (F).w, acc.w); }
        ACC4(w0 * u0, f00); ACC4(w0 * u1, f01); ACC4(w0 * u2, f02); ACC4(w0 * u3, f03);
        ACC4(w1 * u0, f10); ACC4(w1 * u1, f11); ACC4(w1 * u2, f12); ACC4(w1 * u3, f13);
        ACC4(w2 * u0, f20); ACC4(w2 * u1, f21); ACC4(w2 * u2, f22); ACC4(w2 * u3, f23);
        ACC4(w3 * u0, f30); ACC4(w3 * u1, f31); ACC4(w3 * u2, f32); ACC4(w3 * u3, f33);
#undef ACC4

        // tile[bin][c], channel index XOR-swizzled so the writeback's
        // (c fixed, bin varying) reads spread across banks.
        const unsigned xsw = (((unsigned)bin >> 2) & 7u) << 2;
        float* dst = &tile[bin * CCH + ((unsigned)(lane << 2) ^ xsw)];
        *(float4*)dst = acc;   // 0.25 already folded into row weights
    }

    __syncthreads();

    // ---- writeback: contiguous 256*49 floats, coalesced float4 stores ----
    float* oreg = out + (size_t)roi * (CCH * SS);
    for (int i = t; i < (CCH * SS) / 4; i += 512) {
        const int f0 = i * 4;
        float4 v;
        {
            const int f = f0 + 0;
            const int c = f / SS, bn = f - c * SS;
            v.x = tile[bn * CCH + (c ^ ((((unsigned)bn >> 2) & 7u) << 2))];
        }
        {
            const int f = f0 + 1;
            const int c = f / SS, bn = f - c * SS;
            v.y = tile[bn * CCH + (c ^ ((((unsigned)bn >> 2) & 7u) << 2))];
        }
        {
            const int f = f0 + 2;
            const int c = f / SS, bn = f - c * SS;
            v.z = tile[bn * CCH + (c ^ ((((unsigned)bn >> 2) & 7u) << 2))];
        }
        {
            const int f = f0 + 3;
            const int c = f / SS, bn = f - c * SS;
            v.w = tile[bn * CCH + (c ^ ((((unsigned)bn >> 2) & 7u) << 2))];
        }
        *(float4*)(oreg + f0) = v;
    }
}

extern "C" void kernel_launch(void* const* d_in, const int* in_sizes, int n_in,
                              void* d_out, int out_size, void* d_ws, size_t ws_size,
                              hipStream_t stream) {
    const float* fm2  = (const float*)d_in[0];
    const float* fm3  = (const float*)d_in[1];
    const float* fm4  = (const float*)d_in[2];
    const float* fm5  = (const float*)d_in[3];
    const float* rois = (const float*)d_in[4];
    float* out = (float*)d_out;

    roialign_kernel<<<BATCH * NROI, 512, 0, stream>>>(fm2, fm3, fm4, fm5, rois, out);
}

// Round 11
// 63.920 us; speedup vs baseline: 1.8325x; 1.8325x over previous
//
#include <hip/hip_runtime.h>

// ROIAlign (FPN, multi-level) for MI355X — FINAL (R9 restored).
// Inputs (f32): fm2 [4,256,256,256] s4 | fm3 [4,128,128,256] s8
//               fm4 [4,64,64,256] s16  | fm5 [4,32,32,256] s32
//               rois [4,512,4] (x1,y1,x2,y2)
// Output (f32): [4,512,256,7,7]
//
// Proven structure (64 us): 1 ROI/block, 512 thr, LUT-precomputed sample
// offsets/weights, per-bin corner dedup with SCALAR (wave-uniform) load
// guards, 16 batched float4 gathers (full MLP), LDS-staged XOR-swizzled
// tile, coalesced float4 writeback.
// Tested and rejected: per-lane guards (-3.2x, exec-mask), occupancy via
// float2/2-phase (-1.2x), VGPR cap 512,6 (-1.8x, kills load batch),
// cross-bin row cache (-1.6x, serial dep chain), fewer load instrs (null).

constexpr int S     = 7;
constexpr int SS    = 49;
constexpr int CCH   = 256;
constexpr int NROI  = 512;
constexpr int BATCH = 4;

__global__ __launch_bounds__(512, 4) void roialign_kernel(
    const float* __restrict__ fm2, const float* __restrict__ fm3,
    const float* __restrict__ fm4, const float* __restrict__ fm5,
    const float* __restrict__ rois, float* __restrict__ out)
{
    __shared__ float    tile[SS * CCH];   // 50176 B, XOR-swizzled channel index
    __shared__ float    s_wyh[14], s_wyl[14], s_wxh[14], s_wxl[14];
    __shared__ unsigned s_ry0[14], s_ry1[14], s_cx0[14], s_cx1[14];
    __shared__ float    s_bw[SS][4];      // merged row weights per bin (pre-scaled 0.25)
    __shared__ float    s_bu[SS][4];      // merged col weights per bin
    __shared__ unsigned s_bm[SS];         // survive mask: rows bits0-3, cols bits4-7

    const int roi = blockIdx.x;           // 0 .. B*N-1
    const int b   = roi >> 9;

    // ---- wave-uniform prologue ----
    const float x1  = rois[roi * 4 + 0];
    const float y1v = rois[roi * 4 + 1];
    const float x2  = rois[roi * 4 + 2];
    const float y2v = rois[roi * 4 + 3];

    const float area = (y2v - y1v) * (x2 - x1);
    const float lraw = logf(sqrtf(area) * (1.0f / 224.0f)) * 1.4426950408889634f + 4.0f;
    int lvl = (int)rintf(lraw);
    lvl = lvl < 2 ? 2 : (lvl > 5 ? 5 : lvl);

    const float* fm; int H; float scale;
    if (lvl == 2)      { fm = fm2; H = 256; scale = 0.25f;    }
    else if (lvl == 3) { fm = fm3; H = 128; scale = 0.125f;   }
    else if (lvl == 4) { fm = fm4; H = 64;  scale = 0.0625f;  }
    else               { fm = fm5; H = 32;  scale = 0.03125f; }
    const int W = H;
    fm += (size_t)b * H * W * CCH;

    const float bx1 = x1 * scale, by1 = y1v * scale;
    const float rw  = fmaxf(x2 * scale - bx1, 1.0f);
    const float rh  = fmaxf(y2v * scale - by1, 1.0f);
    const float stx = rw * (1.0f / 7.0f);
    const float sty = rh * (1.0f / 7.0f);

    const int t = threadIdx.x;

    // ---- sample LUT: 14 y entries (wave 0) + 14 x entries (wave 1) ----
    if (t < 14) {
        const int k = t;
        const float yy = by1 + ((float)k + 0.5f) * 0.5f * sty;
        const float Hf = (float)H;
        const bool  v  = (yy > -1.0f) && (yy < Hf);
        const float yc = fminf(fmaxf(yy, 0.0f), Hf - 1.0f);
        const int   y0 = (int)floorf(yc);
        const int   y1i = min(y0 + 1, H - 1);
        const float ly = yc - (float)y0;
        s_wyl[k] = v ? ly : 0.0f;
        s_wyh[k] = v ? 1.0f - ly : 0.0f;
        s_ry0[k] = (unsigned)(y0  * W * (CCH * 4));   // byte offset of fm row
        s_ry1[k] = (unsigned)(y1i * W * (CCH * 4));
    } else if (t >= 64 && t < 78) {
        const int k = t - 64;
        const float xx = bx1 + ((float)k + 0.5f) * 0.5f * stx;
        const float Wf = (float)W;
        const bool  v  = (xx > -1.0f) && (xx < Wf);
        const float xc = fminf(fmaxf(xx, 0.0f), Wf - 1.0f);
        const int   x0 = (int)floorf(xc);
        const int   x1i = min(x0 + 1, W - 1);
        const float lx = xc - (float)x0;
        s_wxl[k] = v ? lx : 0.0f;
        s_wxh[k] = v ? 1.0f - lx : 0.0f;
        s_cx0[k] = (unsigned)(x0  * (CCH * 4));       // byte offset of fm col
        s_cx1[k] = (unsigned)(x1i * (CCH * 4));
    }
    __syncthreads();

    // ---- per-bin merged weights + survive mask (one thread per bin) ----
    if (t < SS) {
        const int sy = t / 7, sx = t - sy * 7;
        const int ky = sy << 1, kx = sx << 1;

        float w0 = s_wyh[ky], w1 = s_wyl[ky], w2 = s_wyh[ky + 1], w3 = s_wyl[ky + 1];
        {
            const unsigned rA = s_ry0[ky], rB = s_ry1[ky];
            const unsigned rC = s_ry0[ky + 1], rD = s_ry1[ky + 1];
            const bool eBA = (rB == rA);
            if (eBA) { w0 += w1; w1 = 0.f; }
            const bool eCA = (rC == rA);
            const bool eCB = !eCA && (rC == rB);
            if (eCA) w0 += w2; else if (eCB) w1 += w2;
            if (eCA || eCB) w2 = 0.f;
            const bool eDA = (rD == rA);
            const bool eDB = !eDA && (rD == rB);
            const bool eDC = !eDA && !eDB && (rD == rC);
            if (eDA) w0 += w3; else if (eDB) w1 += w3; else if (eDC) w2 += w3;
            if (eDA || eDB || eDC) w3 = 0.f;
        }
        float u0 = s_wxh[kx], u1 = s_wxl[kx], u2 = s_wxh[kx + 1], u3 = s_wxl[kx + 1];
        {
            const unsigned cA = s_cx0[kx], cB = s_cx1[kx];
            const unsigned cC = s_cx0[kx + 1], cD = s_cx1[kx + 1];
            const bool eBA = (cB == cA);
            if (eBA) { u0 += u1; u1 = 0.f; }
            const bool eCA = (cC == cA);
            const bool eCB = !eCA && (cC == cB);
            if (eCA) u0 += u2; else if (eCB) u1 += u2;
            if (eCA || eCB) u2 = 0.f;
            const bool eDA = (cD == cA);
            const bool eDB = !eDA && (cD == cB);
            const bool eDC = !eDA && !eDB && (cD == cC);
            if (eDA) u0 += u3; else if (eDB) u1 += u3; else if (eDC) u2 += u3;
            if (eDA || eDB || eDC) u3 = 0.f;
        }
        // fold the 2x2 bin-average (0.25) into the row weights
        s_bw[t][0] = w0 * 0.25f; s_bw[t][1] = w1 * 0.25f;
        s_bw[t][2] = w2 * 0.25f; s_bw[t][3] = w3 * 0.25f;
        s_bu[t][0] = u0; s_bu[t][1] = u1; s_bu[t][2] = u2; s_bu[t][3] = u3;
        s_bm[t] = (w0 != 0.f ? 0x01u : 0u) | (w1 != 0.f ? 0x02u : 0u)
                | (w2 != 0.f ? 0x04u : 0u) | (w3 != 0.f ? 0x08u : 0u)
                | (u0 != 0.f ? 0x10u : 0u) | (u1 != 0.f ? 0x20u : 0u)
                | (u2 != 0.f ? 0x40u : 0u) | (u3 != 0.f ? 0x80u : 0u);
    }
    __syncthreads();

    // ---- compute: one bin per wave-pass, 4 channels (float4) per lane ----
    const int lane = t & 63;
    const int wv   = t >> 6;                       // 0..7
    const unsigned cb = (unsigned)(lane << 4);     // byte offset within pixel

    const char* __restrict__ fmb = (const char*)fm;
    const float4 z4 = make_float4(0.f, 0.f, 0.f, 0.f);

    for (int bin = wv; bin < SS; bin += 8) {
        const int sy = bin / 7;
        const int sx = bin - sy * 7;
        const int ky = sy << 1, kx = sx << 1;

        // scalar survive mask -> wave-uniform s_cbranch guards
        const unsigned m = (unsigned)__builtin_amdgcn_readfirstlane((int)s_bm[bin]);

        const float w0 = s_bw[bin][0], w1 = s_bw[bin][1];
        const float w2 = s_bw[bin][2], w3 = s_bw[bin][3];
        const float u0 = s_bu[bin][0], u1 = s_bu[bin][1];
        const float u2 = s_bu[bin][2], u3 = s_bu[bin][3];

        const unsigned rA = s_ry0[ky],     rB = s_ry1[ky];
        const unsigned rC = s_ry0[ky + 1], rD = s_ry1[ky + 1];
        const unsigned cA = s_cx0[kx],     cB = s_cx1[kx];
        const unsigned cC = s_cx0[kx + 1], cD = s_cx1[kx + 1];

#define LD4(OFF) (*(const float4*)(fmb + (OFF)))
        float4 f00 = z4, f01 = z4, f02 = z4, f03 = z4;
        float4 f10 = z4, f11 = z4, f12 = z4, f13 = z4;
        float4 f20 = z4, f21 = z4, f22 = z4, f23 = z4;
        float4 f30 = z4, f31 = z4, f32 = z4, f33 = z4;

        if ((m & 0x11u) == 0x11u) f00 = LD4(rA + cA + cb);
        if ((m & 0x21u) == 0x21u) f01 = LD4(rA + cB + cb);
        if ((m & 0x41u) == 0x41u) f02 = LD4(rA + cC + cb);
        if ((m & 0x81u) == 0x81u) f03 = LD4(rA + cD + cb);
        if ((m & 0x12u) == 0x12u) f10 = LD4(rB + cA + cb);
        if ((m & 0x22u) == 0x22u) f11 = LD4(rB + cB + cb);
        if ((m & 0x42u) == 0x42u) f12 = LD4(rB + cC + cb);
        if ((m & 0x82u) == 0x82u) f13 = LD4(rB + cD + cb);
        if ((m & 0x14u) == 0x14u) f20 = LD4(rC + cA + cb);
        if ((m & 0x24u) == 0x24u) f21 = LD4(rC + cB + cb);
        if ((m & 0x44u) == 0x44u) f22 = LD4(rC + cC + cb);
        if ((m & 0x84u) == 0x84u) f23 = LD4(rC + cD + cb);
        if ((m & 0x18u) == 0x18u) f30 = LD4(rD + cA + cb);
        if ((m & 0x28u) == 0x28u) f31 = LD4(rD + cB + cb);
        if ((m & 0x48u) == 0x48u) f32 = LD4(rD + cC + cb);
        if ((m & 0x88u) == 0x88u) f33 = LD4(rD + cD + cb);
#undef LD4

        float4 acc = z4;
#define ACC4(Wt, F) { const float pw_ = (Wt); \
        acc.x = fmaf(pw_, (F).x, acc.x); acc.y = fmaf(pw_, (F).y, acc.y); \
        acc.z = fmaf(pw_, (F).z, acc.z); acc.w = fmaf(pw_, (F).w, acc.w); }
        ACC4(w0 * u0, f00); ACC4(w0 * u1, f01); ACC4(w0 * u2, f02); ACC4(w0 * u3, f03);
        ACC4(w1 * u0, f10); ACC4(w1 * u1, f11); ACC4(w1 * u2, f12); ACC4(w1 * u3, f13);
        ACC4(w2 * u0, f20); ACC4(w2 * u1, f21); ACC4(w2 * u2, f22); ACC4(w2 * u3, f23);
        ACC4(w3 * u0, f30); ACC4(w3 * u1, f31); ACC4(w3 * u2, f32); ACC4(w3 * u3, f33);
#undef ACC4

        // tile[bin][c], channel index XOR-swizzled so the writeback's
        // (c fixed, bin varying) reads spread across banks.
        const unsigned xsw = (((unsigned)bin >> 2) & 7u) << 2;
        float* dst = &tile[bin * CCH + ((unsigned)(lane << 2) ^ xsw)];
        *(float4*)dst = acc;   // 0.25 already folded into row weights
    }

    __syncthreads();

    // ---- writeback: contiguous 256*49 floats, coalesced float4 stores ----
    float* oreg = out + (size_t)roi * (CCH * SS);
    for (int i = t; i < (CCH * SS) / 4; i += 512) {
        const int f0 = i * 4;
        float4 v;
        {
            const int f = f0 + 0;
            const int c = f / SS, bn = f - c * SS;
            v.x = tile[bn * CCH + (c ^ ((((unsigned)bn >> 2) & 7u) << 2))];
        }
        {
            const int f = f0 + 1;
            const int c = f / SS, bn = f - c * SS;
            v.y = tile[bn * CCH + (c ^ ((((unsigned)bn >> 2) & 7u) << 2))];
        }
        {
            const int f = f0 + 2;
            const int c = f / SS, bn = f - c * SS;
            v.z = tile[bn * CCH + (c ^ ((((unsigned)bn >> 2) & 7u) << 2))];
        }
        {
            const int f = f0 + 3;
            const int c = f / SS, bn = f - c * SS;
            v.w = tile[bn * CCH + (c ^ ((((unsigned)bn >> 2) & 7u) << 2))];
        }
        *(float4*)(oreg + f0) = v;
    }
}

extern "C" void kernel_launch(void* const* d_in, const int* in_sizes, int n_in,
                              void* d_out, int out_size, void* d_ws, size_t ws_size,
                              hipStream_t stream) {
    const float* fm2  = (const float*)d_in[0];
    const float* fm3  = (const float*)d_in[1];
    const float* fm4  = (const float*)d_in[2];
    const float* fm5  = (const float*)d_in[3];
    const float* rois = (const float*)d_in[4];
    float* out = (float*)d_out;

    roialign_kernel<<<BATCH * NROI, 512, 0, stream>>>(fm2, fm3, fm4, fm5, rois, out);
}